// Round 10
// baseline (179.671 us; speedup 1.0000x reference)
//
#include <hip/hip_runtime.h>
#include <math.h>

#define T_TOK 8192
#define A_DIM 1024
#define E_DIM 512
#define S_SPAN 32768
#define HID 150

typedef __attribute__((ext_vector_type(8))) short short8;
typedef __attribute__((ext_vector_type(4))) float f32x4;
typedef __attribute__((ext_vector_type(4))) unsigned int u32x4;
typedef __attribute__((ext_vector_type(4))) unsigned short u16x4;

__device__ __forceinline__ unsigned short f2bf(float f) {
    unsigned int u = __builtin_bit_cast(unsigned int, f);
    u += 0x7FFFu + ((u >> 16) & 1u);          // RNE
    return (unsigned short)(u >> 16);
}
__device__ __forceinline__ float bf2f(unsigned int h16) {
    unsigned int u = h16 << 16;
    return __builtin_bit_cast(float, u);
}

// ---------------------------------------------------------------------------
// fused prep: input cast (fp32->bf16) + 6 weight transposes + width proj
// ---------------------------------------------------------------------------
#define NS4 (T_TOK * A_DIM / 4)   // 2097152
#define NE4 (T_TOK * E_DIM / 4)   // 1048576
#define NCAST ((NS4 + NE4) / 256) // 12288 exactly

struct WConv { const float* src; unsigned short* dst; int K0; int Kpad; int nblk; };
struct PrepTab {
    const float* s; const float* e; unsigned short* sd; unsigned short* ed;
    WConv g[6];
    const float* wt; const float* Ws1w; float* PW;
};

__global__ __launch_bounds__(256) void prep_kernel(PrepTab tab) {
    int b = blockIdx.x;
    if (b < NCAST) {
        int idx = b * 256 + threadIdx.x;
        const float* src; unsigned short* dst;
        if (idx < NS4) { src = tab.s; dst = tab.sd; }
        else { idx -= NS4; src = tab.e; dst = tab.ed; }
        f32x4 v = *(const f32x4*)(src + (size_t)idx * 4);
        u16x4 o;
        o.x = f2bf(v.x); o.y = f2bf(v.y); o.z = f2bf(v.z); o.w = f2bf(v.w);
        *(u16x4*)(dst + (size_t)idx * 4) = o;
        return;
    }
    b -= NCAST;
    #pragma unroll
    for (int gi = 0; gi < 6; ++gi) {
        if (b < tab.g[gi].nblk) {
            int idx = b * 256 + threadIdx.x;               // idx = k*160 + j
            int Kpad = tab.g[gi].Kpad;
            if (idx < Kpad * 160) {
                int k = idx / 160, j = idx - k * 160;
                float v = (j < HID && k < tab.g[gi].K0)
                          ? tab.g[gi].src[(size_t)k * HID + j] : 0.f;   // coalesced read
                tab.g[gi].dst[(size_t)j * Kpad + k] = f2bf(v);          // scattered write
            }
            return;
        }
        b -= tab.g[gi].nblk;
    }
    // width projection: 9 blocks
    int j = threadIdx.x;
    if (j < HID) {
        float acc = 0.f;
        for (int k = 0; k < 20; ++k)
            acc = fmaf(tab.wt[b * 20 + k], tab.Ws1w[k * HID + j], acc);
        tab.PW[b * HID + j] = acc;
    }
}

// ---------------------------------------------------------------------------
// unified MFMA GEMM, double-buffered + software-pipelined (R9 structure).
// per group: C[M x 160] = A(bf16,[M x K]) @ W(bf16,[160 x K] k-contig)
// block = 4 waves x 16 rows = 64 rows, 10 n-tiles, BK=64, 2 LDS buffers.
// LDW=72: 46.1 KB -> 3 blocks/CU. 144 B rows: 16B-aligned, 2-way alias (free).
// ---------------------------------------------------------------------------
struct GG {
    const unsigned short* A; int lda;
    const unsigned short* W; int K; int nrb;
    unsigned short* outh; int ldo;
    const float* bias; int relu;
    const float* dotv; const float* dotb; float* dotout;
};
struct GTab { GG g[4]; int ng; };

template <int TAG>
__global__ __launch_bounds__(256) void gemm_fused(GTab tab) {
    constexpr int LDW = 72;
    __shared__ unsigned short WtL[2][160 * LDW];

    int b = blockIdx.x;
    int gi = 0;
    while (gi < tab.ng - 1 && b >= tab.g[gi].nrb) { b -= tab.g[gi].nrb; ++gi; }
    const GG G = tab.g[gi];

    const int tid = threadIdx.x;
    const int wid = tid >> 6;
    const int lane = tid & 63;
    const int l15 = lane & 15;
    const int quad = lane >> 4;
    const int row0 = b * 64 + wid * 16 + l15;
    const int K = G.K;
    const int nch = K >> 6;
    const unsigned short* Arow = G.A + (size_t)row0 * G.lda;

    // staging registers for W chunk: 1280 16B units / 256 thr = 5 each
    u32x4 stg[5];
    int sn[5], sk[5];
    #pragma unroll
    for (int i = 0; i < 5; ++i) { int u = tid + i * 256; sn[i] = u >> 3; sk[i] = (u & 7) * 8; }

    f32x4 acc[10];
    #pragma unroll
    for (int nt = 0; nt < 10; ++nt) acc[nt] = (f32x4){0.f, 0.f, 0.f, 0.f};

    #pragma unroll
    for (int i = 0; i < 5; ++i)
        stg[i] = *(const u32x4*)(G.W + (size_t)sn[i] * K + sk[i]);
    short8 avc0 = *(const short8*)(Arow + quad * 8);
    short8 avc1 = *(const short8*)(Arow + 32 + quad * 8);
    #pragma unroll
    for (int i = 0; i < 5; ++i)
        *(u32x4*)&WtL[0][sn[i] * LDW + sk[i]] = stg[i];
    __syncthreads();

    for (int c = 0; c < nch; ++c) {
        const int pb = c & 1;
        short8 avn0, avn1;
        const bool more = (c + 1 < nch);
        if (more) {
            const int kn = (c + 1) << 6;
            #pragma unroll
            for (int i = 0; i < 5; ++i)
                stg[i] = *(const u32x4*)(G.W + (size_t)sn[i] * K + kn + sk[i]);
            avn0 = *(const short8*)(Arow + kn + quad * 8);
            avn1 = *(const short8*)(Arow + kn + 32 + quad * 8);
        }
        #pragma unroll
        for (int nt = 0; nt < 10; ++nt) {
            short8 bv0 = *(const short8*)&WtL[pb][(nt * 16 + l15) * LDW + quad * 8];
            acc[nt] = __builtin_amdgcn_mfma_f32_16x16x32_bf16(avc0, bv0, acc[nt], 0, 0, 0);
            short8 bv1 = *(const short8*)&WtL[pb][(nt * 16 + l15) * LDW + 32 + quad * 8];
            acc[nt] = __builtin_amdgcn_mfma_f32_16x16x32_bf16(avc1, bv1, acc[nt], 0, 0, 0);
        }
        if (more) {
            #pragma unroll
            for (int i = 0; i < 5; ++i)
                *(u32x4*)&WtL[pb ^ 1][sn[i] * LDW + sk[i]] = stg[i];
            avc0 = avn0; avc1 = avn1;
        }
        __syncthreads();
    }

    const int rbase = b * 64 + wid * 16 + quad * 4;
    if (G.dotout) {
        float part[4] = {0.f, 0.f, 0.f, 0.f};
        #pragma unroll
        for (int nt = 0; nt < 10; ++nt) {
            int col = nt * 16 + l15;
            float bv_ = (col < HID) ? G.bias[col] : 0.f;
            float vv = (col < HID) ? G.dotv[col] : 0.f;
            #pragma unroll
            for (int r = 0; r < 4; ++r)
                part[r] += fmaxf(acc[nt][r] + bv_, 0.f) * vv;
        }
        #pragma unroll
        for (int r = 0; r < 4; ++r) {
            float p = part[r];
            #pragma unroll
            for (int off = 1; off < 16; off <<= 1) p += __shfl_xor(p, off);
            if (l15 == 0) G.dotout[rbase + r] = p + G.dotb[0];
        }
    } else {
        #pragma unroll
        for (int nt = 0; nt < 10; ++nt) {
            int col = nt * 16 + l15;
            float bv_ = (G.bias != nullptr && col < HID) ? G.bias[col] : 0.f;
            #pragma unroll
            for (int r = 0; r < 4; ++r) {
                int row = rbase + r;
                float v = acc[nt][r] + bv_;
                if (G.relu) v = fmaxf(v, 0.f);
                G.outh[(size_t)row * G.ldo + col] = f2bf(v);
            }
        }
    }
}

// ---------------------------------------------------------------------------
// span layer-1: one wave per span; bf16 P gathers via packed u32 pairs.
// writes SH1 bf16 [S x 192] cols 0..149.
// ---------------------------------------------------------------------------
__global__ __launch_bounds__(256) void span_l1_kernel(const float* __restrict__ attns,
                                                      const int* __restrict__ starts,
                                                      const int* __restrict__ lens,
                                                      const unsigned short* __restrict__ Ps,
                                                      const unsigned short* __restrict__ Pe,
                                                      const unsigned short* __restrict__ Pm,
                                                      const float* __restrict__ PW,
                                                      const float* __restrict__ bs1,
                                                      unsigned short* __restrict__ SH1) {
    const int wid = threadIdx.x >> 6, lane = threadIdx.x & 63;
    const int s = blockIdx.x * 4 + wid;
    const int start = starts[s];
    const int len = lens[s];

    const int iv = min(start + lane, T_TOK - 1);
    float a = (lane <= len) ? attns[iv] : -INFINITY;
    float m = a;
    #pragma unroll
    for (int off = 32; off; off >>= 1) m = fmaxf(m, __shfl_xor(m, off));
    float e = (lane <= len) ? __expf(a - m) : 0.f;
    float ssum = e;
    #pragma unroll
    for (int off = 32; off; off >>= 1) ssum += __shfl_xor(ssum, off);
    float wv = e / ssum;

    float wl[10]; int il[10];
    #pragma unroll
    for (int l = 0; l < 10; ++l) { wl[l] = __shfl(wv, l); il[l] = __shfl(iv, l); }

    const int end = start + len;
    const int width = len + 1;
    const int bucket = (width >= 1) + (width >= 2) + (width >= 3) + (width >= 4) +
                       (width >= 8) + (width >= 16) + (width >= 32) + (width >= 64);

    const unsigned short* ps = Ps + (size_t)start * 160;
    const unsigned short* pe = Pe + (size_t)end * 160;
    const float* pw = PW + bucket * HID;

    // 75 column-pairs: p = lane (0..63), then p = 64+lane (lane<11)
    for (int p = lane; p < 75; p += 64) {
        const int j = 2 * p;
        unsigned int u0 = *(const unsigned int*)(ps + j);
        unsigned int u1 = *(const unsigned int*)(pe + j);
        float a0 = bs1[j]     + bf2f(u0 & 0xffff) + bf2f(u1 & 0xffff) + pw[j];
        float a1 = bs1[j + 1] + bf2f(u0 >> 16)    + bf2f(u1 >> 16)    + pw[j + 1];
        #pragma unroll
        for (int l = 0; l < 10; ++l) {
            unsigned int um = *(const unsigned int*)(Pm + (size_t)il[l] * 160 + j);
            a0 = fmaf(wl[l], bf2f(um & 0xffff), a0);
            a1 = fmaf(wl[l], bf2f(um >> 16), a1);
        }
        unsigned int packed = (unsigned int)f2bf(fmaxf(a0, 0.f)) |
                              ((unsigned int)f2bf(fmaxf(a1, 0.f)) << 16);
        *(unsigned int*)(SH1 + (size_t)s * 192 + j) = packed;
    }
}

extern "C" void kernel_launch(void* const* d_in, const int* in_sizes, int n_in,
                              void* d_out, int out_size, void* d_ws, size_t ws_size,
                              hipStream_t stream) {
    const float* states = (const float*)d_in[0];
    const float* embeds = (const float*)d_in[1];
    const int* span_starts = (const int*)d_in[2];
    const int* span_lengths = (const int*)d_in[3];
    const float* Wa1 = (const float*)d_in[4];
    const float* ba1 = (const float*)d_in[5];
    const float* Wa2 = (const float*)d_in[6];
    const float* ba2 = (const float*)d_in[7];
    const float* Wa3 = (const float*)d_in[8];
    const float* ba3 = (const float*)d_in[9];
    const float* width_table = (const float*)d_in[10];
    const float* Ws1 = (const float*)d_in[11];
    const float* bs1 = (const float*)d_in[12];
    const float* Ws2 = (const float*)d_in[13];
    const float* bs2 = (const float*)d_in[14];
    const float* Ws3 = (const float*)d_in[15];
    const float* bs3 = (const float*)d_in[16];
    float* out = (float*)d_out;

    // ---- workspace layout ----
    char* w = (char*)d_ws;
    unsigned short* WtA  = (unsigned short*)w;  w += 480 * 1024 * 2;
    unsigned short* WtE  = (unsigned short*)w;  w += 160 * 512 * 2;
    unsigned short* Wa2t = (unsigned short*)w;  w += 160 * 192 * 2;
    unsigned short* Ws2t = (unsigned short*)w;  w += 160 * 192 * 2;
    float* PW    = (float*)w;                   w += 5632;
    float* attns = (float*)w;                   w += 8192 * 4;
    unsigned short* Sbf = (unsigned short*)w;   w += (size_t)T_TOK * A_DIM * 2;
    unsigned short* Ebf = (unsigned short*)w;   w += (size_t)T_TOK * E_DIM * 2;
    unsigned short* Psh = (unsigned short*)w;   w += (size_t)T_TOK * 160 * 2;   // bf16
    unsigned short* Peh = (unsigned short*)w;   w += (size_t)T_TOK * 160 * 2;   // bf16
    unsigned short* Pmh = (unsigned short*)w;   w += (size_t)T_TOK * 160 * 2;   // bf16
    unsigned short* H1A = (unsigned short*)w;   w += (size_t)T_TOK * 192 * 2;   // bf16
    unsigned short* SH1 = (unsigned short*)w;   w += (size_t)S_SPAN * 192 * 2;  // bf16
    // No memsets: pad cols (0xAA poison = finite bf16) multiply zeroed W rows.

    // ---- fused prep: cast + weight transposes + width proj ----
    PrepTab pt;
    pt.s = states; pt.e = embeds; pt.sd = Sbf; pt.ed = Ebf;
    pt.g[0] = { Wa1,              WtA,              1024, 1024, (160*1024 + 255)/256 };
    pt.g[1] = { Ws1,              WtA + 160*1024,   1024, 1024, (160*1024 + 255)/256 };
    pt.g[2] = { Ws1 + 1024*150,   WtA + 320*1024,   1024, 1024, (160*1024 + 255)/256 };
    pt.g[3] = { Ws1 + 2048*150,   WtE,               512,  512, (160*512  + 255)/256 };
    pt.g[4] = { Wa2,              Wa2t,              150,  192, (160*192  + 255)/256 };
    pt.g[5] = { Ws2,              Ws2t,              150,  192, (160*192  + 255)/256 };
    pt.wt = width_table; pt.Ws1w = Ws1 + 2560*150; pt.PW = PW;
    int wblk = 0; for (int i = 0; i < 6; ++i) wblk += pt.g[i].nblk;
    prep_kernel<<<NCAST + wblk + 9, 256, 0, stream>>>(pt);

    GG z = {};

    // ---- fused GEMM1+2: 4 groups, 512 blocks (3 blocks/CU) ----
    GTab t1; t1.ng = 4;
    t1.g[0] = z; t1.g[0].A = Sbf; t1.g[0].lda = 1024; t1.g[0].W = WtA;            t1.g[0].K = 1024;
    t1.g[0].nrb = 128; t1.g[0].outh = H1A; t1.g[0].ldo = 192; t1.g[0].bias = ba1; t1.g[0].relu = 1;
    t1.g[1] = z; t1.g[1].A = Sbf; t1.g[1].lda = 1024; t1.g[1].W = WtA + 160*1024; t1.g[1].K = 1024;
    t1.g[1].nrb = 128; t1.g[1].outh = Psh; t1.g[1].ldo = 160;
    t1.g[2] = z; t1.g[2].A = Sbf; t1.g[2].lda = 1024; t1.g[2].W = WtA + 320*1024; t1.g[2].K = 1024;
    t1.g[2].nrb = 128; t1.g[2].outh = Peh; t1.g[2].ldo = 160;
    t1.g[3] = z; t1.g[3].A = Ebf; t1.g[3].lda = 512;  t1.g[3].W = WtE;            t1.g[3].K = 512;
    t1.g[3].nrb = 128; t1.g[3].outh = Pmh; t1.g[3].ldo = 160;
    gemm_fused<1><<<512, 256, 0, stream>>>(t1);

    // ---- attn layer2 + fused layer3 dot -> attns ----
    GTab t2; t2.ng = 1;
    t2.g[0] = z; t2.g[0].A = H1A; t2.g[0].lda = 192; t2.g[0].W = Wa2t; t2.g[0].K = 192;
    t2.g[0].nrb = 128; t2.g[0].bias = ba2; t2.g[0].dotv = Wa3; t2.g[0].dotb = ba3; t2.g[0].dotout = attns;
    gemm_fused<2><<<128, 256, 0, stream>>>(t2);

    // ---- span layer1 -> SH1 (bf16) ----
    span_l1_kernel<<<S_SPAN / 4, 256, 0, stream>>>(attns, span_starts, span_lengths,
                                                   Psh, Peh, Pmh, PW, bs1, SH1);

    // ---- span layer2 + fused layer3 dot -> out ----
    GTab t3; t3.ng = 1;
    t3.g[0] = z; t3.g[0].A = SH1; t3.g[0].lda = 192; t3.g[0].W = Ws2t; t3.g[0].K = 192;
    t3.g[0].nrb = 512; t3.g[0].bias = bs2; t3.g[0].dotv = Ws3; t3.g[0].dotb = bs3; t3.g[0].dotout = out;
    gemm_fused<3><<<512, 256, 0, stream>>>(t3);
}